// Round 9
// baseline (130.563 us; speedup 1.0000x reference)
//
#include <hip/hip_runtime.h>

// NTN: out[n,k] = relu( cos(x1 @ W1[k], x2 @ W2[k]) + [x1,x2]·V[k] + b[k] )
// N=32768, D=128, K=16.
// R12 = R3 schedule/tiling verbatim, MFMA shape 16x16x32 -> 32x32x16.
// R11 proved bench-main ~69us is fixed harness overhead; only main matters.
// R3..R10: occupancy/vmcnt/pipe-migration all null -> per-CU pipe SUM (~LDS 20
// + MFMA 16.6 + VALU ~12) is the cost. This round halves the MFMA instruction
// count (512 vs 1024/wave, 8.07 vs 2x4.85 cyc -> matrix 13.4us), collapses the
// epilogue to 3 shfl_xor(32)/k (vs 12), and fuses part2+b via one padded
// 32x32 MFMA pass. LDS bytes/staging/grid/barriers identical to R3.
// Layouts: C-map verified (m74/m101): col=lane&31, row=(reg&3)+8*(reg>>2)+4*(lane>>5).
// A/B lane pattern: [m|n = lane&31][k = (lane>>5)*8 + j] (extrapolated from the
// working 16x16 pattern [lane&15][(lane>>4)*8+j]).
//  - wsW chunk cc = k*2+h (32KB, same numbering/staging): unit u =
//    side*1024 + t*512 + s*64 + lane; frag[j] = W_side[k][d = s*16+(lane>>5)*8+j]
//    [e = (h*2+t)*32 + (lane&31)].
//  - wsV: unit cs2*64+lane: frag[j] = (lane&31)<16 ? V[lane&31][cs2*16+(lane>>5)*8+j] : 0
//    (k padded to 32 rows).
//  - launch_bounds(256,1): R8 lesson — arg2=2 caps VGPR at 128 and spills.

typedef __attribute__((ext_vector_type(8))) __bf16 bf16x8;
typedef __attribute__((ext_vector_type(8))) unsigned short us8;
typedef __attribute__((ext_vector_type(16))) float f32x16;

static __device__ __forceinline__ unsigned short f2bf(float f) {
  unsigned u = __float_as_uint(f);
  u += 0x7FFFu + ((u >> 16) & 1u);   // round-to-nearest-even
  return (unsigned short)(u >> 16);
}

static __device__ __forceinline__ bf16x8 as_bf(us8 u) {
  bf16x8 r;
  __builtin_memcpy(&r, &u, sizeof(r));
  return r;
}

// ---------------- prep (elementwise, 32x32 fragment layout) ----------------
__global__ void ntn_prep(const float* __restrict__ W1, const float* __restrict__ W2,
                         const float* __restrict__ V,
                         unsigned short* __restrict__ wsW, unsigned short* __restrict__ wsV) {
  int e2 = blockIdx.x * 256 + threadIdx.x;
  if (e2 < 524288) {
    int j = e2 & 7, tu = e2 >> 3;
    int u = tu & 2047, cc = tu >> 11;
    int lane = u & 63, s = (u >> 6) & 7, t = (u >> 9) & 1, side = (u >> 10) & 1;
    int h = cc & 1, k = cc >> 1;
    int l31 = lane & 31, g = lane >> 5;
    int d = s * 16 + g * 8 + j;
    int e = (h * 2 + t) * 32 + l31;
    const float* W = side ? W2 : W1;
    wsW[e2] = f2bf(W[k * 16384 + d * 128 + e]);
  } else if (e2 < 524288 + 8192) {
    int v2 = e2 - 524288;
    int j = v2 & 7, u = v2 >> 3;
    int lane = u & 63, cs2 = u >> 6;           // 0..15
    int l31 = lane & 31, g = lane >> 5;
    int c = cs2 * 16 + g * 8 + j;
    float val = (l31 < 16) ? V[l31 * 256 + c] : 0.f;   // k padded to 32 rows
    wsV[v2] = f2bf(val);
  }
}

// ---------------- main ----------------
__global__ __launch_bounds__(256, 1) void ntn_main(
    const float* __restrict__ x1, const float* __restrict__ x2,
    const float* __restrict__ b,
    const unsigned short* __restrict__ wsW, const unsigned short* __restrict__ wsV,
    float* __restrict__ out) {
  __shared__ uint4 ldsW[2][2048];   // two 32KB chunk slots = 64KB

  const int tid = threadIdx.x;
  const int lane = tid & 63, wave = tid >> 6;
  const int l31 = lane & 31, g = lane >> 5;
  const int kh = blockIdx.x & 1;          // k range [8kh, 8kh+8)
  const int rb = blockIdx.x >> 1;         // 128-row group
  const int rowbase = rb * 128 + wave * 32;

  const f32x16 zero16 = {0.f,0.f,0.f,0.f,0.f,0.f,0.f,0.f,0.f,0.f,0.f,0.f,0.f,0.f,0.f,0.f};

  // async stage of one 32KB chunk into an LDS slot (verbatim R3; layout-agnostic)
  auto stage = [&](int cc, int slot) {
    const unsigned short* src = wsW + (size_t)cc * 16384 + (size_t)(wave * 512 + lane) * 8;
    uint4* dst = &ldsW[slot][wave * 512];
#pragma unroll
    for (int i = 0; i < 8; ++i)
      __builtin_amdgcn_global_load_lds(
          (__attribute__((address_space(1))) void*)(void*)(src + i * 512),
          (__attribute__((address_space(3))) void*)(dst + i * 64), 16, 0, 0);
  };

  stage(kh * 16, 0);   // first chunk of our k range

  // ---- X fragments (B-operand, 32x32): frag[j] = X[rowbase + l31][s*16 + g*8 + j]
  bf16x8 xb[2][8];
#pragma unroll
  for (int side = 0; side < 2; ++side) {
    const float* xp0 = side ? x2 : x1;
#pragma unroll
    for (int s = 0; s < 8; ++s) {
      const float* p = xp0 + (size_t)(rowbase + l31) * 128 + s * 16 + g * 8;
      float4 v0 = *(const float4*)p;
      float4 v1 = *(const float4*)(p + 4);
      us8 uu;
      uu[0] = f2bf(v0.x); uu[1] = f2bf(v0.y); uu[2] = f2bf(v0.z); uu[3] = f2bf(v0.w);
      uu[4] = f2bf(v1.x); uu[5] = f2bf(v1.y); uu[6] = f2bf(v1.z); uu[7] = f2bf(v1.w);
      xb[side][s] = as_bf(uu);
    }
  }

  // ---- part2 + b: one padded 32x32 pass. A = Vpad[32 x 16c-block], B = xb.
  // accPv[reg] = part2 for k-row (reg&3)+8*(reg>>2)+4*g (regs 0..7 valid), n = l31.
  float accP[8];
  {
    f32x16 a = zero16;
#pragma unroll
    for (int cs2 = 0; cs2 < 16; ++cs2) {
      bf16x8 vf = as_bf(*(const us8*)(wsV + (size_t)(cs2 * 64 + lane) * 8));
      a = __builtin_amdgcn_mfma_f32_32x32x16_bf16(vf, xb[cs2 >> 3][cs2 & 7], a, 0, 0, 0);
    }
#pragma unroll
    for (int r = 0; r < 8; ++r)
      accP[r] = a[r] + b[(r & 3) + 8 * ((r >> 2) & 1) + 4 * g];
  }

  float nm = 0.f, q1 = 0.f, q2 = 0.f;

  // compute one e-half (2 e-tiles of 32, both sides) from an LDS slot
  auto compute = [&](int slot) {
#pragma unroll
    for (int t = 0; t < 2; ++t) {
      bf16x8 wa[8], wb[8];
#pragma unroll
      for (int s = 0; s < 8; ++s) {
        wa[s] = as_bf(*(const us8*)&ldsW[slot][t * 512 + s * 64 + lane]);
        wb[s] = as_bf(*(const us8*)&ldsW[slot][1024 + t * 512 + s * 64 + lane]);
      }
      f32x16 a1 = zero16, a2 = zero16;
#pragma unroll
      for (int s = 0; s < 8; ++s)
        a1 = __builtin_amdgcn_mfma_f32_32x32x16_bf16(wa[s], xb[0][s], a1, 0, 0, 0);
#pragma unroll
      for (int s = 0; s < 8; ++s)
        a2 = __builtin_amdgcn_mfma_f32_32x32x16_bf16(wb[s], xb[1][s], a2, 0, 0, 0);
#pragma unroll
      for (int r = 0; r < 16; ++r) {
        nm += a1[r] * a2[r];
        q1 += a1[r] * a1[r];
        q2 += a2[r] * a2[r];
      }
    }
  };

#pragma unroll 1
  for (int kk = 0; kk < 8; ++kk) {
    const int cbase = kh * 16 + 2 * kk;
    __syncthreads();                       // chunk (kk, h=0) in slot0; slot1 free
    stage(cbase + 1, 1);
    compute(0);
    __syncthreads();                       // chunk (kk, h=1) in slot1; slot0 free
    if (kk < 7) stage(cbase + 2, 0);
    compute(1);

    const int k = kh * 8 + kk;
    // e-reduction: own 16 rows + partner lane's 16 via one xor-32 fold
    float n = nm, s1 = q1, s2 = q2;
    n  += __shfl_xor(n, 32);
    s1 += __shfl_xor(s1, 32);
    s2 += __shfl_xor(s2, 32);
    float d1 = fmaxf(sqrtf(s1), 1e-8f);
    float d2 = fmaxf(sqrtf(s2), 1e-8f);
    float p1 = n / (d1 * d2);
    int rr = (k & 3) | ((k >> 1) & 4);     // (k&3) + 4*((k>>3)&1)
    float pc = rr == 0 ? accP[0] : rr == 1 ? accP[1] : rr == 2 ? accP[2]
             : rr == 3 ? accP[3] : rr == 4 ? accP[4] : rr == 5 ? accP[5]
             : rr == 6 ? accP[6] : accP[7];
    if (g == ((k >> 2) & 1))
      out[(size_t)(rowbase + l31) * 16 + k] = fmaxf(p1 + pc, 0.f);
    nm = 0.f; q1 = 0.f; q2 = 0.f;
  }
}

extern "C" void kernel_launch(void* const* d_in, const int* in_sizes, int n_in,
                              void* d_out, int out_size, void* d_ws, size_t ws_size,
                              hipStream_t stream) {
  const float* x1 = (const float*)d_in[0];
  const float* x2 = (const float*)d_in[1];
  const float* W1 = (const float*)d_in[2];
  const float* W2 = (const float*)d_in[3];
  const float* V  = (const float*)d_in[4];
  const float* b  = (const float*)d_in[5];
  float* out = (float*)d_out;
  unsigned short* wsW = (unsigned short*)d_ws;
  unsigned short* wsV = wsW + (size_t)65536 * 8;   // 1MB offset

  ntn_prep<<<2080, 256, 0, stream>>>(W1, W2, V, wsW, wsV);
  ntn_main<<<512, 256, 0, stream>>>(x1, x2, b, wsW, wsV, out);
}